// Round 6
// baseline (346.896 us; speedup 1.0000x reference)
//
#include <hip/hip_runtime.h>

// Chain of 9 Linear layers, no activation => collapse to one affine map.
// dims: 784 -> 69 -> 31 -> 10 -> ... -> 10
//
// R12: DEPTH-4 PREFETCH (8 outstanding nt loads/lane) on the R11 structure.
//   Ledger: pattern changes (R9 fused, R10 contiguous) = regressions;
//   MLP changes = wins (R11 depth-2+nt: -17.6us). Little's law: reads need
//   in-flight bytes = BW x loaded-latency; at congested latency 2-4k cyc
//   the prior 64KB/CU pool is marginal. Depth-4 doubles it to 128KB/CU
//   (128B/lane, 8KB/wave, 16 waves/CU). FP order, lane->j ownership,
//   butterfly, writes byte-identical to R8/R11 -> absmax 0.0009765625.
//   Null result (318 +- 4) would kill the MLP theory -> structural floor.
//
// MAIN (R8 base): 2 rows/lane. s = t&7 owns j = jb*32+s*4; rows (t>>3),
//   +64. x loads coalesced (8 rows x 128B whole lines per instr, x2 row
//   sets), non-temporal (no L3 alloc). Weights in LDS, padded 11*float4
//   per j-quad: start bank quad (3s+o)&7 -> all 8 addr groups disjoint,
//   8-way broadcast: conflict-free. Tail 784=24*32+16: weight j4 196..199
//   zeroed, x addr clamped to 780 (clamped elements hit zero weights).
//   LDS 35.2KB; grid 512 -> 2 blocks/CU, 16 waves/CU.
//
// prep_all (R7, proven): 18 blocks x 512; every block redundantly
//   computes the collapse chain S8 = W8*...*W1 in its own LDS, folds its
//   512-entry slice of Wt2 from LOCAL LDS; block 0 emits beff.
//
// Wt2 layout: [200 j-quads][11 float4]; entry (j4, o<10) = {W[o][j4*4+k]};
// o==10 and j4 in [196,200) are zero padding.

typedef float vf4 __attribute__((ext_vector_type(4)));

__device__ __forceinline__ vf4 ntld(const float* p) {
    return __builtin_nontemporal_load((const vf4*)p);
}

__global__ void prep_all(
    const float* __restrict__ W0,
    const float* __restrict__ W1, const float* __restrict__ b1,
    const float* __restrict__ W2, const float* __restrict__ b2,
    const float* __restrict__ W3, const float* __restrict__ b3,
    const float* __restrict__ W4, const float* __restrict__ b4,
    const float* __restrict__ W5, const float* __restrict__ b5,
    const float* __restrict__ W6, const float* __restrict__ b6,
    const float* __restrict__ W7, const float* __restrict__ b7,
    const float* __restrict__ W8, const float* __restrict__ b8,
    const float* __restrict__ b0,
    float* __restrict__ Wt2, float* __restrict__ beff)
{
    __shared__ float Sa[31 * 69], Sb[31 * 69];
    __shared__ float da[31], db[31];
    const int t = threadIdx.x;
    const int nt = blockDim.x;

    for (int i = t; i < 31 * 69; i += nt) Sa[i] = W1[i];
    for (int i = t; i < 31; i += nt) da[i] = b1[i];
    __syncthreads();

    for (int i = t; i < 10 * 69; i += nt) {
        int o = i / 69, c = i - o * 69;
        float s = 0.f;
        for (int k = 0; k < 31; k++) s += W2[o * 31 + k] * Sa[k * 69 + c];
        Sb[i] = s;
    }
    for (int i = t; i < 10; i += nt) {
        float s = b2[i];
        for (int k = 0; k < 31; k++) s += W2[i * 31 + k] * da[k];
        db[i] = s;
    }
    __syncthreads();

    const float* Wk[6] = { W3, W4, W5, W6, W7, W8 };
    const float* bk[6] = { b3, b4, b5, b6, b7, b8 };
    int src = 1;  // runtime ternaries: gfx950 rejects arrays of LDS pointers
    for (int st = 0; st < 6; st++) {
        const float* W = Wk[st];
        const float* bb = bk[st];
        float* S  = src ? Sb : Sa;
        float* D  = src ? Sa : Sb;
        float* dd = src ? db : da;
        float* dn = src ? da : db;
        for (int i = t; i < 10 * 69; i += nt) {
            int o = i / 69, c = i - o * 69;
            float s = 0.f;
            for (int k = 0; k < 10; k++) s += W[o * 10 + k] * S[k * 69 + c];
            D[i] = s;
        }
        for (int i = t; i < 10; i += nt) {
            float s = bb[i];
            for (int k = 0; k < 10; k++) s += W[i * 10 + k] * dd[k];
            dn[i] = s;
        }
        __syncthreads();
        src ^= 1;
    }

    float* S  = src ? Sb : Sa;   // src back to 1 after 6 flips -> Sb
    float* dd = src ? db : da;

    if (blockIdx.x == 0) {
        for (int i = t; i < 10; i += nt) {
            float s = dd[i];
            for (int k = 0; k < 69; k++) s += S[i * 69 + k] * b0[k];
            beff[i] = s;
        }
    }

    int e = blockIdx.x * nt + t;   // 0..9215, need 0..8799
    if (e < 8800) {
        int j4 = e / 44, rem = e - j4 * 44;
        float val = 0.f;
        if (rem < 40) {
            int o = rem >> 2, k = rem & 3, j = j4 * 4 + k;
            if (j < 784) {
                for (int u = 0; u < 69; u++) val += S[o * 69 + u] * W0[u * 784 + j];
            }
        }
        Wt2[e] = val;
    }
}

// ---- main (R12: R8 + nt loads + depth-4 prefetch) ----

__global__ __launch_bounds__(512, 4) void linear_main(
    const float* __restrict__ x, const float* __restrict__ Wt2,
    const float* __restrict__ beff, float* __restrict__ out)
{
    __shared__ float4 wlds[2200];   // 35.2 KB
    const int t = threadIdx.x;
    const int s = t & 7;                         // j-segment within row group
    const long row0 = (long)blockIdx.x * 128 + (t >> 3);   // second row = row0+64
    const float* xr0 = x + row0 * 784;
    const float* xr1 = xr0 + (long)64 * 784;
    const int j0 = s * 4;

    // stage weights (independent of the x loads)
    {
        const float4* wg = (const float4*)Wt2;
        for (int i = t; i < 2200; i += 512) wlds[i] = wg[i];
    }

    float acc0[10], acc1[10];
#pragma unroll
    for (int o = 0; o < 10; o++) { acc0[o] = 0.f; acc1[o] = 0.f; }

    // depth-4 prefetch issued before the barrier (nt: no L3/L2 allocation).
    // Any jb >= 25 clamps to addr 780 (in-row, weights there are zero).
#define JADDR(JB) ((JB) * 32 + j0 > 780 ? 780 : (JB) * 32 + j0)
    vf4 p0a = ntld(xr0 + JADDR(0)), p0b = ntld(xr1 + JADDR(0));
    vf4 p1a = ntld(xr0 + JADDR(1)), p1b = ntld(xr1 + JADDR(1));
    vf4 p2a = ntld(xr0 + JADDR(2)), p2b = ntld(xr1 + JADDR(2));
    vf4 p3a = ntld(xr0 + JADDR(3)), p3b = ntld(xr1 + JADDR(3));
    __syncthreads();

#define BODY(XC0, XC1, JB) { \
    const float4* wrow = &wlds[((JB) * 8 + s) * 11]; \
    _Pragma("unroll") \
    for (int o = 0; o < 10; o++) { \
        float4 wv = wrow[o]; \
        acc0[o] = fmaf((XC0).x, wv.x, acc0[o]); \
        acc0[o] = fmaf((XC0).y, wv.y, acc0[o]); \
        acc0[o] = fmaf((XC0).z, wv.z, acc0[o]); \
        acc0[o] = fmaf((XC0).w, wv.w, acc0[o]); \
        acc1[o] = fmaf((XC1).x, wv.x, acc1[o]); \
        acc1[o] = fmaf((XC1).y, wv.y, acc1[o]); \
        acc1[o] = fmaf((XC1).z, wv.z, acc1[o]); \
        acc1[o] = fmaf((XC1).w, wv.w, acc1[o]); \
    } }

    for (int jb = 0; jb < 24; jb += 4) {
        // consume p0 (holds jb), refill p0 for jb+4; etc. 8 loads in flight.
        { vf4 c0 = p0a, c1 = p0b;
          p0a = ntld(xr0 + JADDR(jb + 4)); p0b = ntld(xr1 + JADDR(jb + 4));
          BODY(c0, c1, jb); }
        { vf4 c0 = p1a, c1 = p1b;
          p1a = ntld(xr0 + JADDR(jb + 5)); p1b = ntld(xr1 + JADDR(jb + 5));
          BODY(c0, c1, jb + 1); }
        { vf4 c0 = p2a, c1 = p2b;
          p2a = ntld(xr0 + JADDR(jb + 6)); p2b = ntld(xr1 + JADDR(jb + 6));
          BODY(c0, c1, jb + 2); }
        { vf4 c0 = p3a, c1 = p3b;
          p3a = ntld(xr0 + JADDR(jb + 7)); p3b = ntld(xr1 + JADDR(jb + 7));
          BODY(c0, c1, jb + 3); }
    }
    BODY(p0a, p0b, 24);   // p0 refilled at jb=20 with JADDR(24)

#undef BODY
#undef JADDR

    // butterfly sum over the 8 lanes sharing each row (bits 0..2 of lane id)
#pragma unroll
    for (int m = 1; m < 8; m <<= 1)
#pragma unroll
        for (int o = 0; o < 10; o++) {
            acc0[o] += __shfl_xor(acc0[o], m, 64);
            acc1[o] += __shfl_xor(acc1[o], m, 64);
        }

    // lanes s<5 write float2 per row (out + row*10 is 8B-aligned; 40B per row)
    if (s < 5) {
        float lo0 = 0.f, hi0 = 0.f, lo1 = 0.f, hi1 = 0.f;
#pragma unroll
        for (int o = 0; o < 5; o++) {
            if (s == o) {                         // cndmask chain
                lo0 = acc0[2 * o]; hi0 = acc0[2 * o + 1];
                lo1 = acc1[2 * o]; hi1 = acc1[2 * o + 1];
            }
        }
        float be0 = beff[s * 2], be1 = beff[s * 2 + 1];
        *(float2*)(out + row0 * 10 + s * 2) = make_float2(lo0 + be0, hi0 + be1);
        *(float2*)(out + (row0 + 64) * 10 + s * 2) = make_float2(lo1 + be0, hi1 + be1);
    }
}

extern "C" void kernel_launch(void* const* d_in, const int* in_sizes, int n_in,
                              void* d_out, int out_size, void* d_ws, size_t ws_size,
                              hipStream_t stream) {
    const float* x  = (const float*)d_in[0];
    const float* W0 = (const float*)d_in[1];
    const float* b0 = (const float*)d_in[2];
    const float* W1 = (const float*)d_in[3];
    const float* b1 = (const float*)d_in[4];
    const float* W2 = (const float*)d_in[5];
    const float* b2 = (const float*)d_in[6];
    const float* W3 = (const float*)d_in[7];
    const float* b3 = (const float*)d_in[8];
    const float* W4 = (const float*)d_in[9];
    const float* b4 = (const float*)d_in[10];
    const float* W5 = (const float*)d_in[11];
    const float* b5 = (const float*)d_in[12];
    const float* W6 = (const float*)d_in[13];
    const float* b6 = (const float*)d_in[14];
    const float* W7 = (const float*)d_in[15];
    const float* b7 = (const float*)d_in[16];
    const float* W8 = (const float*)d_in[17];
    const float* b8 = (const float*)d_in[18];

    float* ws   = (float*)d_ws;
    float* Wt2  = ws;            // 8800 floats: [200 j4][11 float4]
    float* beff = ws + 8800;     // 10 floats

    float* out = (float*)d_out;
    const int B = in_sizes[0] / 784;  // 65536

    prep_all<<<18, 512, 0, stream>>>(W0, W1, b1, W2, b2, W3, b3, W4, b4,
                                     W5, b5, W6, b6, W7, b7, W8, b8,
                                     b0, Wt2, beff);
    linear_main<<<B / 128, 512, 0, stream>>>(x, Wt2, beff, out);
}

// Round 7
// 333.633 us; speedup vs baseline: 1.0398x; 1.0398x over previous
//
#include <hip/hip_runtime.h>

// Chain of 9 Linear layers, no activation => collapse to one affine map.
// dims: 784 -> 69 -> 31 -> 10 -> ... -> 10
//
// R13: SPLIT CACHE CLASSES on the R11 base (depth-2 + nt was the proven
//   best, 318.3us; depth-4 regressed -> reverted).
//   Evidence: R9 FETCH ~103MB for a 205MB zero-reuse pass => ~50% of x
//   stays L3-resident across iterations (fills don't flush it). Two
//   delivery paths exist: L3-hit and HBM. R11 (all-nt) uses only HBM
//   (2.5 TB/s); R8 (all-cached) churned L3 allocation (205MB > share)
//   and both paths crawled. R13: odd blocks load x non-temporally (no L3
//   alloc), even blocks load cached (their ~102MB subset fits L3, no
//   churn). All 512 blocks co-resident (2/CU) -> both classes stream
//   CONCURRENTLY: HBM ~42us for the nt half, L3 serves the other half in
//   parallel. Both arms are FP-identical -> absmax 0.0009765625.
//   Pre-commit: >=315us kills this theory -> declare structural ceiling.
//
// MAIN (R8/R11 base): 2 rows/lane. s = t&7 owns j = jb*32+s*4; rows
//   (t>>3), +64. x loads coalesced (8 rows x 128B whole lines per instr,
//   x2 row sets), depth-2 prefetch. Weights in LDS, padded 11*float4 per
//   j-quad: start bank quad (3s+o)&7 -> all 8 addr groups disjoint,
//   8-way broadcast: conflict-free. Tail 784=24*32+16: weight j4
//   196..199 zeroed, x addr clamped to 780 (clamped elements hit zero
//   weights). LDS 35.2KB; grid 512 -> 2 blocks/CU, 16 waves/CU.
//
// prep_all (R7, proven): 18 blocks x 512; every block redundantly
//   computes the collapse chain S8 = W8*...*W1 in its own LDS, folds its
//   512-entry slice of Wt2 from LOCAL LDS; block 0 emits beff.
//
// Wt2 layout: [200 j-quads][11 float4]; entry (j4, o<10) = {W[o][j4*4+k]};
// o==10 and j4 in [196,200) are zero padding.

typedef float vf4 __attribute__((ext_vector_type(4)));

template<bool NT>
__device__ __forceinline__ vf4 ldx(const float* p) {
    if constexpr (NT) return __builtin_nontemporal_load((const vf4*)p);
    else              return *(const vf4*)p;
}

__global__ void prep_all(
    const float* __restrict__ W0,
    const float* __restrict__ W1, const float* __restrict__ b1,
    const float* __restrict__ W2, const float* __restrict__ b2,
    const float* __restrict__ W3, const float* __restrict__ b3,
    const float* __restrict__ W4, const float* __restrict__ b4,
    const float* __restrict__ W5, const float* __restrict__ b5,
    const float* __restrict__ W6, const float* __restrict__ b6,
    const float* __restrict__ W7, const float* __restrict__ b7,
    const float* __restrict__ W8, const float* __restrict__ b8,
    const float* __restrict__ b0,
    float* __restrict__ Wt2, float* __restrict__ beff)
{
    __shared__ float Sa[31 * 69], Sb[31 * 69];
    __shared__ float da[31], db[31];
    const int t = threadIdx.x;
    const int nt = blockDim.x;

    for (int i = t; i < 31 * 69; i += nt) Sa[i] = W1[i];
    for (int i = t; i < 31; i += nt) da[i] = b1[i];
    __syncthreads();

    for (int i = t; i < 10 * 69; i += nt) {
        int o = i / 69, c = i - o * 69;
        float s = 0.f;
        for (int k = 0; k < 31; k++) s += W2[o * 31 + k] * Sa[k * 69 + c];
        Sb[i] = s;
    }
    for (int i = t; i < 10; i += nt) {
        float s = b2[i];
        for (int k = 0; k < 31; k++) s += W2[i * 31 + k] * da[k];
        db[i] = s;
    }
    __syncthreads();

    const float* Wk[6] = { W3, W4, W5, W6, W7, W8 };
    const float* bk[6] = { b3, b4, b5, b6, b7, b8 };
    int src = 1;  // runtime ternaries: gfx950 rejects arrays of LDS pointers
    for (int st = 0; st < 6; st++) {
        const float* W = Wk[st];
        const float* bb = bk[st];
        float* S  = src ? Sb : Sa;
        float* D  = src ? Sa : Sb;
        float* dd = src ? db : da;
        float* dn = src ? da : db;
        for (int i = t; i < 10 * 69; i += nt) {
            int o = i / 69, c = i - o * 69;
            float s = 0.f;
            for (int k = 0; k < 10; k++) s += W[o * 10 + k] * S[k * 69 + c];
            D[i] = s;
        }
        for (int i = t; i < 10; i += nt) {
            float s = bb[i];
            for (int k = 0; k < 10; k++) s += W[i * 10 + k] * dd[k];
            dn[i] = s;
        }
        __syncthreads();
        src ^= 1;
    }

    float* S  = src ? Sb : Sa;   // src back to 1 after 6 flips -> Sb
    float* dd = src ? db : da;

    if (blockIdx.x == 0) {
        for (int i = t; i < 10; i += nt) {
            float s = dd[i];
            for (int k = 0; k < 69; k++) s += S[i * 69 + k] * b0[k];
            beff[i] = s;
        }
    }

    int e = blockIdx.x * nt + t;   // 0..9215, need 0..8799
    if (e < 8800) {
        int j4 = e / 44, rem = e - j4 * 44;
        float val = 0.f;
        if (rem < 40) {
            int o = rem >> 2, k = rem & 3, j = j4 * 4 + k;
            if (j < 784) {
                for (int u = 0; u < 69; u++) val += S[o * 69 + u] * W0[u * 784 + j];
            }
        }
        Wt2[e] = val;
    }
}

// ---- main (R13: R11 depth-2 pipeline, cache class chosen per block) ----

template<bool NT>
__device__ __forceinline__ void main_body(
    const float* xr0, const float* xr1, const float4* wlds,
    const float* __restrict__ beff, float* __restrict__ out,
    long row0, int s, int j0)
{
    float acc0[10], acc1[10];
#pragma unroll
    for (int o = 0; o < 10; o++) { acc0[o] = 0.f; acc1[o] = 0.f; }

    // depth-2 prefetch issued before the barrier
#define JADDR(JB) ((JB) * 32 + j0 > 780 ? 780 : (JB) * 32 + j0)
    vf4 a0 = ldx<NT>(xr0 + j0),      a1 = ldx<NT>(xr1 + j0);       // jb=0
    vf4 b0 = ldx<NT>(xr0 + 32 + j0), b1 = ldx<NT>(xr1 + 32 + j0);  // jb=1
    __syncthreads();

#define BODY(XC0, XC1, JB) { \
    const float4* wrow = &wlds[((JB) * 8 + s) * 11]; \
    _Pragma("unroll") \
    for (int o = 0; o < 10; o++) { \
        float4 wv = wrow[o]; \
        acc0[o] = fmaf((XC0).x, wv.x, acc0[o]); \
        acc0[o] = fmaf((XC0).y, wv.y, acc0[o]); \
        acc0[o] = fmaf((XC0).z, wv.z, acc0[o]); \
        acc0[o] = fmaf((XC0).w, wv.w, acc0[o]); \
        acc1[o] = fmaf((XC1).x, wv.x, acc1[o]); \
        acc1[o] = fmaf((XC1).y, wv.y, acc1[o]); \
        acc1[o] = fmaf((XC1).z, wv.z, acc1[o]); \
        acc1[o] = fmaf((XC1).w, wv.w, acc1[o]); \
    } }

    for (int jb = 0; jb < 24; jb += 2) {
        // A body: consume a*, refill for jb+2 (clamped addr: tail weights = 0)
        vf4 c0 = a0, c1 = a1;
        a0 = ldx<NT>(xr0 + JADDR(jb + 2));
        a1 = ldx<NT>(xr1 + JADDR(jb + 2));
        BODY(c0, c1, jb);
        // B body: consume b*, refill for jb+3
        vf4 d0 = b0, d1 = b1;
        b0 = ldx<NT>(xr0 + JADDR(jb + 3));
        b1 = ldx<NT>(xr1 + JADDR(jb + 3));
        BODY(d0, d1, jb + 1);
    }
    BODY(a0, a1, 24);   // a* holds JADDR(24), loaded at jb=22

#undef BODY
#undef JADDR

    // butterfly sum over the 8 lanes sharing each row (bits 0..2 of lane id)
#pragma unroll
    for (int m = 1; m < 8; m <<= 1)
#pragma unroll
        for (int o = 0; o < 10; o++) {
            acc0[o] += __shfl_xor(acc0[o], m, 64);
            acc1[o] += __shfl_xor(acc1[o], m, 64);
        }

    // lanes s<5 write float2 per row (out + row*10 is 8B-aligned; 40B per row)
    if (s < 5) {
        float lo0 = 0.f, hi0 = 0.f, lo1 = 0.f, hi1 = 0.f;
#pragma unroll
        for (int o = 0; o < 5; o++) {
            if (s == o) {                         // cndmask chain
                lo0 = acc0[2 * o]; hi0 = acc0[2 * o + 1];
                lo1 = acc1[2 * o]; hi1 = acc1[2 * o + 1];
            }
        }
        float be0 = beff[s * 2], be1 = beff[s * 2 + 1];
        *(float2*)(out + row0 * 10 + s * 2) = make_float2(lo0 + be0, hi0 + be1);
        *(float2*)(out + (row0 + 64) * 10 + s * 2) = make_float2(lo1 + be0, hi1 + be1);
    }
}

__global__ __launch_bounds__(512, 4) void linear_main(
    const float* __restrict__ x, const float* __restrict__ Wt2,
    const float* __restrict__ beff, float* __restrict__ out)
{
    __shared__ float4 wlds[2200];   // 35.2 KB
    const int t = threadIdx.x;
    const int s = t & 7;                         // j-segment within row group
    const long row0 = (long)blockIdx.x * 128 + (t >> 3);   // second row = row0+64
    const float* xr0 = x + row0 * 784;
    const float* xr1 = xr0 + (long)64 * 784;
    const int j0 = s * 4;

    // stage weights (independent of the x loads)
    {
        const float4* wg = (const float4*)Wt2;
        for (int i = t; i < 2200; i += 512) wlds[i] = wg[i];
    }

    // block-parity cache class: odd = non-temporal (HBM stream, no L3
    // alloc), even = cached (its ~102MB subset L3-fits with no churn).
    // All 512 blocks co-resident -> both paths stream concurrently.
    if (blockIdx.x & 1) main_body<true >(xr0, xr1, wlds, beff, out, row0, s, j0);
    else                main_body<false>(xr0, xr1, wlds, beff, out, row0, s, j0);
}

extern "C" void kernel_launch(void* const* d_in, const int* in_sizes, int n_in,
                              void* d_out, int out_size, void* d_ws, size_t ws_size,
                              hipStream_t stream) {
    const float* x  = (const float*)d_in[0];
    const float* W0 = (const float*)d_in[1];
    const float* b0 = (const float*)d_in[2];
    const float* W1 = (const float*)d_in[3];
    const float* b1 = (const float*)d_in[4];
    const float* W2 = (const float*)d_in[5];
    const float* b2 = (const float*)d_in[6];
    const float* W3 = (const float*)d_in[7];
    const float* b3 = (const float*)d_in[8];
    const float* W4 = (const float*)d_in[9];
    const float* b4 = (const float*)d_in[10];
    const float* W5 = (const float*)d_in[11];
    const float* b5 = (const float*)d_in[12];
    const float* W6 = (const float*)d_in[13];
    const float* b6 = (const float*)d_in[14];
    const float* W7 = (const float*)d_in[15];
    const float* b7 = (const float*)d_in[16];
    const float* W8 = (const float*)d_in[17];
    const float* b8 = (const float*)d_in[18];

    float* ws   = (float*)d_ws;
    float* Wt2  = ws;            // 8800 floats: [200 j4][11 float4]
    float* beff = ws + 8800;     // 10 floats

    float* out = (float*)d_out;
    const int B = in_sizes[0] / 784;  // 65536

    prep_all<<<18, 512, 0, stream>>>(W0, W1, b1, W2, b2, W3, b3, W4, b4,
                                     W5, b5, W6, b6, W7, b7, W8, b8,
                                     b0, Wt2, beff);
    linear_main<<<B / 128, 512, 0, stream>>>(x, Wt2, beff, out);
}